// Round 9
// baseline (381.027 us; speedup 1.0000x reference)
//
#include <hip/hip_runtime.h>

typedef unsigned short u16;
typedef __bf16 bf16x8 __attribute__((ext_vector_type(8)));
typedef float f32x4 __attribute__((ext_vector_type(4)));

#define B_ 2
#define T_ 1024
#define D_ 1024
#define H_ 64
#define HS_ 64
#define FF_ 4096
#define SZ_QKV 8388608L
// softmax in exp2 domain: scale = (1/sqrt(64)) * log2(e); folded into Q staging
#define S_SCALE 0.1803368801111f

__device__ __forceinline__ float bf2f(u16 u) {
  union { unsigned int v; float f; } x; x.v = ((unsigned int)u) << 16; return x.f;
}
__device__ __forceinline__ u16 f2bf(float f) {
  union { float f; unsigned int v; } x; x.f = f;
  unsigned int r = x.v + 0x7fffu + ((x.v >> 16) & 1u);
  return (u16)(r >> 16);
}
__device__ __forceinline__ u16 f2bf_rtz(float f) {
  union { float f; unsigned int v; } x; x.f = f;
  return (u16)(x.v >> 16);
}

typedef __attribute__((address_space(3))) unsigned int lds_u32;
typedef __attribute__((address_space(1))) const unsigned int glb_u32;
__device__ __forceinline__ void gload_lds16(const void* g, void* l) {
  __builtin_amdgcn_global_load_lds((glb_u32*)g, (lds_u32*)l, 16, 0, 0);
}

// ---------------------------------------------------------------------------
// Consolidated pre-pass: x cvt + all weight transpose/convert (+Wo row perm).
__global__ __launch_bounds__(256) void prep(
    const float* __restrict__ x, const float* __restrict__ Wq,
    const float* __restrict__ Wk, const float* __restrict__ Wv,
    const float* __restrict__ Wo, const float* __restrict__ W1,
    const float* __restrict__ W2,
    u16* __restrict__ xb, u16* __restrict__ Wqkvt, u16* __restrict__ Wot,
    u16* __restrict__ W1t, u16* __restrict__ W2t)
{
  __shared__ float tile[64][65];
  int id = blockIdx.x;
  if (id < 1024) {           // x: fp32 -> bf16, 2048 elems/block
    const long i = ((long)id * 256 + threadIdx.x) * 8;
    float4 a = *(const float4*)(x + i);
    float4 b = *(const float4*)(x + i + 4);
    union { uint4 v; u16 u[8]; } o;
    o.u[0]=f2bf(a.x); o.u[1]=f2bf(a.y); o.u[2]=f2bf(a.z); o.u[3]=f2bf(a.w);
    o.u[4]=f2bf(b.x); o.u[5]=f2bf(b.y); o.u[6]=f2bf(b.z); o.u[7]=f2bf(b.w);
    *(uint4*)(xb + i) = o.v;
    return;
  }
  id -= 1024;
  const float* in; u16* out; long ibase, obase; int in_rs, out_rs, r0, c0;
  if (id < 3072) {           // Wq/Wk/Wv: [64][1024][64] -> [w*4096+z*64+c][r]
    const int w = id >> 10, rem = id & 1023;
    const int z = rem >> 4, rt = rem & 15;
    in = (w == 0) ? Wq : (w == 1) ? Wk : Wv;
    ibase = (long)z * 65536; in_rs = 64; r0 = rt * 64; c0 = 0;
    out = Wqkvt + (long)w * 4194304;
    obase = (long)z * 65536; out_rs = 1024;
  } else if (id < 4096) {    // Wo row-permuted: Wot'[c][h*64+e] = Wo[e*64+h][c]
    const int rem = id - 3072;
    const int z = rem >> 4, ct = rem & 15;      // z = h
    in = Wo; ibase = (long)z * 1024; in_rs = 65536; r0 = 0; c0 = ct * 64;
    out = Wot; obase = (long)z * 64; out_rs = 4096;
  } else if (id < 5120) {    // W1 [1024][4096] -> W1t[c][r]
    const int rem = id - 4096;
    const int rt = rem >> 6, ct = rem & 63;
    in = W1; ibase = 0; in_rs = 4096; r0 = rt * 64; c0 = ct * 64;
    out = W1t; obase = 0; out_rs = 1024;
  } else {                   // W2 [4096][1024] -> W2t[c][r]
    const int rem = id - 5120;
    const int rt = rem >> 4, ct = rem & 15;
    in = W2; ibase = 0; in_rs = 1024; r0 = rt * 64; c0 = ct * 64;
    out = W2t; obase = 0; out_rs = 4096;
  }
  const int t = threadIdx.x, lr = t >> 4, lc4 = (t & 15) * 4;
  #pragma unroll
  for (int j = 0; j < 4; ++j) {
    float4 f = *(const float4*)(in + ibase + (long)(r0 + lr + j * 16) * in_rs + c0 + lc4);
    tile[lr + j * 16][lc4]     = f.x;
    tile[lr + j * 16][lc4 + 1] = f.y;
    tile[lr + j * 16][lc4 + 2] = f.z;
    tile[lr + j * 16][lc4 + 3] = f.w;
  }
  __syncthreads();
  const int cr = t >> 3, ch = t & 7;
  #pragma unroll
  for (int j2 = 0; j2 < 2; ++j2) {
    const int crr = cr + j2 * 32;
    union { uint4 v; u16 u[8]; } o;
    #pragma unroll
    for (int i = 0; i < 8; ++i) o.u[i] = f2bf(tile[ch * 8 + i][crr]);
    *(uint4*)(out + obase + (long)(c0 + crr) * out_rs + r0 + ch * 8) = o.v;
  }
}

// ---------------------------------------------------------------------------
// Minimal-barrier pipelined bf16 GEMM with register read-ahead (r8 structure).
// BM=256, BN=128, BK=64, 512 threads (8 waves, 4M x 2N), per-wave 64x64.
// Triple-buffered LDS, ONE s_barrier + ONE counted vmcnt(6) per K-tile.
// ALL 16 ds_read_b128 issued right after the barrier; compiler emits
// progressive counted lgkmcnt so each MFMA cluster's LDS wait overlaps the
// previous cluster's MFMAs. MFMA clusters k-sub-outer; epilogue j-innermost.
// LDS swizzle: stored chunk phys = log ^ (row&7) via pre-swizzled global src.
// EPI: 1 bias+relu->bf16, 2 QKV scatter (q,k row-major; V TRANSPOSED
// v_t[bh][e][t] so attention can stage V with vector LDS writes),
// 3 fp32 partial (no bias).
template<int EPI, int LDA, int LDB>
__global__ __launch_bounds__(512, 2) void gemm8b(
    const u16* __restrict__ A, const u16* __restrict__ Bt, u16* __restrict__ C,
    const float* __restrict__ bias, int K, int koff, int ldc)
{
  __shared__ __attribute__((aligned(16))) u16 As[3][256 * 64];  // 96 KiB
  __shared__ __attribute__((aligned(16))) u16 Bs[3][128 * 64];  // 48 KiB
  const int nwg = gridDim.x, cpx = nwg >> 3;
  const int sid = (blockIdx.x & 7) * cpx + (blockIdx.x >> 3);
  const int bm = sid & 7, bn = sid >> 3;
  const int bz = blockIdx.z;
  const long ko = (long)bz * koff;
  const int tid = threadIdx.x, wave = tid >> 6, lane = tid & 63;
  const int quad = lane >> 4, l16 = lane & 15;
  const int wm = (wave >> 1) * 64;            // 4 M-waves
  const int wn = (wave & 1) * 64;             // 2 N-waves
  const int slog = ((tid & 7) ^ ((tid >> 3) & 7)) * 8;  // staging src pre-swizzle
  const int srow = tid >> 3;                            // 0..63
  const int ph0 = ((quad)     ^ (l16 & 7)) * 8;         // k-sub 0
  const int ph1 = ((4 + quad) ^ (l16 & 7)) * 8;         // k-sub 1

  const u16* Ag = A + (long)(bm * 256) * LDA + ko + slog;
  const u16* Bg = Bt + (long)(bn * 128) * LDB + ko + slog;

  f32x4 acc[4][4];
  #pragma unroll
  for (int i = 0; i < 4; ++i)
    #pragma unroll
    for (int j = 0; j < 4; ++j) acc[i][j] = (f32x4){0.f, 0.f, 0.f, 0.f};

  const int nK = K >> 6;

  auto STAGE_A = [&](int d, int t, int a) {
    gload_lds16(Ag + (long)(a * 64 + srow) * LDA + (t << 6),
                (u16*)As[d] + a * 4096 + tid * 8);
  };
  auto STAGE_B = [&](int d, int t, int b) {
    gload_lds16(Bg + (long)(b * 64 + srow) * LDB + (t << 6),
                (u16*)Bs[d] + b * 4096 + tid * 8);
  };

  // prologue: tiles 0 and 1 fully staged
  #pragma unroll
  for (int a = 0; a < 4; ++a) STAGE_A(0, 0, a);
  STAGE_B(0, 0, 0); STAGE_B(0, 0, 1);
  #pragma unroll
  for (int a = 0; a < 4; ++a) STAGE_A(1, 1, a);
  STAGE_B(1, 1, 0); STAGE_B(1, 1, 1);

  bf16x8 af[4][2], bf[4][2];
  int cur = 0;
  for (int t = 0; t < nK; ++t) {
    const int nxt = (cur >= 1) ? cur - 1 : 2;   // (t+2)%3
    const bool st = (t + 2) < nK;
    const u16* Ab = As[cur];
    const u16* Bb = Bs[cur];

    if (t < nK - 1) { asm volatile("s_waitcnt vmcnt(6)" ::: "memory"); }
    else            { asm volatile("s_waitcnt vmcnt(0)" ::: "memory"); }
    __builtin_amdgcn_sched_barrier(0);
    __builtin_amdgcn_s_barrier();
    __builtin_amdgcn_sched_barrier(0);

    // issue ALL tile reads up front (a01,b01 -> b23 -> a23)
    #pragma unroll
    for (int ii = 0; ii < 2; ++ii) {
      const u16* r = Ab + (wm + ii * 16 + l16) * 64;
      af[ii][0] = *(const bf16x8*)(r + ph0);
      af[ii][1] = *(const bf16x8*)(r + ph1);
    }
    #pragma unroll
    for (int jj = 0; jj < 2; ++jj) {
      const u16* r = Bb + (wn + jj * 16 + l16) * 64;
      bf[jj][0] = *(const bf16x8*)(r + ph0);
      bf[jj][1] = *(const bf16x8*)(r + ph1);
    }
    #pragma unroll
    for (int jj = 0; jj < 2; ++jj) {
      const u16* r = Bb + (wn + (2 + jj) * 16 + l16) * 64;
      bf[2 + jj][0] = *(const bf16x8*)(r + ph0);
      bf[2 + jj][1] = *(const bf16x8*)(r + ph1);
    }
    #pragma unroll
    for (int ii = 0; ii < 2; ++ii) {
      const u16* r = Ab + (wm + (2 + ii) * 16 + l16) * 64;
      af[2 + ii][0] = *(const bf16x8*)(r + ph0);
      af[2 + ii][1] = *(const bf16x8*)(r + ph1);
    }

    // cluster 0: a01 x b01 (+ stage A0,A1 of t+2)
    if (st) { STAGE_A(nxt, t + 2, 0); STAGE_A(nxt, t + 2, 1); }
    __builtin_amdgcn_s_setprio(1);
    #pragma unroll
    for (int ks = 0; ks < 2; ++ks)
      #pragma unroll
      for (int ii = 0; ii < 2; ++ii)
        #pragma unroll
        for (int jj = 0; jj < 2; ++jj)
          acc[ii][jj] = __builtin_amdgcn_mfma_f32_16x16x32_bf16(af[ii][ks], bf[jj][ks], acc[ii][jj], 0, 0, 0);
    __builtin_amdgcn_s_setprio(0);

    // cluster 1: a01 x b23 (+ stage A2,A3 of t+2)
    if (st) { STAGE_A(nxt, t + 2, 2); STAGE_A(nxt, t + 2, 3); }
    __builtin_amdgcn_s_setprio(1);
    #pragma unroll
    for (int ks = 0; ks < 2; ++ks)
      #pragma unroll
      for (int ii = 0; ii < 2; ++ii)
        #pragma unroll
        for (int jj = 0; jj < 2; ++jj)
          acc[ii][2 + jj] = __builtin_amdgcn_mfma_f32_16x16x32_bf16(af[ii][ks], bf[2 + jj][ks], acc[ii][2 + jj], 0, 0, 0);
    __builtin_amdgcn_s_setprio(0);

    // cluster 2: a23 x b01 (+ stage B0,B1 of t+2)
    if (st) { STAGE_B(nxt, t + 2, 0); STAGE_B(nxt, t + 2, 1); }
    __builtin_amdgcn_s_setprio(1);
    #pragma unroll
    for (int ks = 0; ks < 2; ++ks)
      #pragma unroll
      for (int ii = 0; ii < 2; ++ii)
        #pragma unroll
        for (int jj = 0; jj < 2; ++jj)
          acc[2 + ii][jj] = __builtin_amdgcn_mfma_f32_16x16x32_bf16(af[2 + ii][ks], bf[jj][ks], acc[2 + ii][jj], 0, 0, 0);
    __builtin_amdgcn_s_setprio(0);

    // cluster 3: a23 x b23
    __builtin_amdgcn_s_setprio(1);
    #pragma unroll
    for (int ks = 0; ks < 2; ++ks)
      #pragma unroll
      for (int ii = 0; ii < 2; ++ii)
        #pragma unroll
        for (int jj = 0; jj < 2; ++jj)
          acc[2 + ii][2 + jj] = __builtin_amdgcn_mfma_f32_16x16x32_bf16(af[2 + ii][ks], bf[2 + jj][ks], acc[2 + ii][2 + jj], 0, 0, 0);
    __builtin_amdgcn_s_setprio(0);
    __builtin_amdgcn_sched_barrier(0);

    cur = (cur == 2) ? 0 : cur + 1;
  }

  // epilogue: j innermost -> consecutive stores per output line
  float bv[4];
  #pragma unroll
  for (int j = 0; j < 4; ++j)
    bv[j] = (EPI == 1) ? bias[bn * 128 + wn + j * 16 + l16] : 0.f;
  #pragma unroll
  for (int i = 0; i < 4; ++i) {
    #pragma unroll
    for (int r = 0; r < 4; ++r) {
      const int row = bm * 256 + wm + i * 16 + quad * 4 + r;
      #pragma unroll
      for (int j = 0; j < 4; ++j) {
        const int col = bn * 128 + wn + j * 16 + l16;
        float vv = acc[i][j][r] + bv[j];
        if (EPI == 1) vv = fmaxf(vv, 0.f);
        if (EPI == 2) {
          const int which = col >> 12, rem = col & 4095;
          const int h = rem >> 6, e = rem & 63;
          const int bb = row >> 10, tt = row & 1023;
          long off;
          if (which == 2)   // v stored TRANSPOSED: v_t[bh][e][t]
            off = 2L * SZ_QKV + ((long)((bb << 6) + h)) * 65536L + (long)e * 1024 + tt;
          else
            off = (long)which * SZ_QKV + ((long)((bb << 6) + h)) * 65536L + (long)tt * 64 + e;
          C[off] = f2bf(vv);
        } else if (EPI == 3) {
          ((float*)C)[(long)bz * 2097152 + (long)row * ldc + col] = vv;
        } else {
          C[(long)row * ldc + col] = f2bf(vv);
        }
      }
    }
  }
}

// ---------------------------------------------------------------------------
// Flash causal attention, no-max variant. Grid (B*H, 16). Block 256 (4 waves).
// V arrives TRANSPOSED from QKV (v_t[bh][e][t]) so Vs[e][t] staging is two
// vector ds_write_b128 per thread (identical to Ks) — the 16 scalar-write
// LDS transpose and its XOR swizzle are gone. PV B-fragment reads are then
// bit-identical in form to QK's Ks reads.
__global__ __launch_bounds__(256) void attn_flash(
    const u16* __restrict__ Q, const u16* __restrict__ Kg,
    const u16* __restrict__ Vt, u16* __restrict__ Om)
{
  __shared__ __attribute__((aligned(16))) u16 Ks[2][64][72];
  __shared__ __attribute__((aligned(16))) u16 Vs[2][64][72];   // [e][t]
  __shared__ __attribute__((aligned(16))) u16 QP[4][16][72];
  const int bh = blockIdx.x;
  const int qt = gridDim.y - 1 - blockIdx.y;   // longest first
  const int b = bh >> 6, h = bh & 63;
  const long base = (long)bh * (T_ * HS_);
  const int tid = threadIdx.x;
  const int wave = tid >> 6, lane = tid & 63, quad = lane >> 4, l16 = lane & 15;
  const int sm = tid >> 2, sc = (tid & 3) * 16;

  // stage Q per-wave, pre-scaled by S_SCALE
  {
    const int qr = lane >> 3, qe = (lane & 7) * 8;
    #pragma unroll
    for (int j = 0; j < 2; ++j) {
      union { uint4 v; u16 u[8]; } a, o;
      a.v = *(const uint4*)(Q + base + (long)(qt * 64 + wave * 16 + qr + j * 8) * HS_ + qe);
      #pragma unroll
      for (int i = 0; i < 8; ++i) o.u[i] = f2bf(bf2f(a.u[i]) * S_SCALE);
      *(uint4*)&QP[wave][qr + j * 8][qe] = o.v;
    }
  }
  bf16x8 aq0 = *(const bf16x8*)&QP[wave][l16][quad * 8];
  bf16x8 aq1 = *(const bf16x8*)&QP[wave][l16][32 + quad * 8];

  float psum[4] = { 0.f, 0.f, 0.f, 0.f };
  f32x4 oacc[4] = { {0,0,0,0}, {0,0,0,0}, {0,0,0,0}, {0,0,0,0} };

  // K tile rows: K[t=sm][e=sc..]; V tile rows: v_t[e=sm][t=kt*64+sc..]
  uint4 kA, kB, vA, vB;
  kA = *(const uint4*)(Kg + base + (long)sm * HS_ + sc);
  kB = *(const uint4*)(Kg + base + (long)sm * HS_ + sc + 8);
  vA = *(const uint4*)(Vt + base + (long)sm * 1024 + sc);
  vB = *(const uint4*)(Vt + base + (long)sm * 1024 + sc + 8);
  {
    *(uint4*)&Ks[0][sm][sc] = kA; *(uint4*)&Ks[0][sm][sc + 8] = kB;
    *(uint4*)&Vs[0][sm][sc] = vA; *(uint4*)&Vs[0][sm][sc + 8] = vB;
  }
  __syncthreads();

  for (int kt = 0; kt <= qt; ++kt) {
    const int cur = kt & 1;
    const bool pf = (kt < qt);
    if (pf) {
      kA = *(const uint4*)(Kg + base + (long)((kt + 1) * 64 + sm) * HS_ + sc);
      kB = *(const uint4*)(Kg + base + (long)((kt + 1) * 64 + sm) * HS_ + sc + 8);
      vA = *(const uint4*)(Vt + base + (long)sm * 1024 + (kt + 1) * 64 + sc);
      vB = *(const uint4*)(Vt + base + (long)sm * 1024 + (kt + 1) * 64 + sc + 8);
    }

    // S = Q @ K^T
    f32x4 sacc[4] = { {0,0,0,0}, {0,0,0,0}, {0,0,0,0}, {0,0,0,0} };
    #pragma unroll
    for (int nt = 0; nt < 4; ++nt) {
      bf16x8 b0 = *(const bf16x8*)&Ks[cur][nt * 16 + l16][quad * 8];
      bf16x8 b1 = *(const bf16x8*)&Ks[cur][nt * 16 + l16][32 + quad * 8];
      sacc[nt] = __builtin_amdgcn_mfma_f32_16x16x32_bf16(aq0, b0, sacc[nt], 0, 0, 0);
      sacc[nt] = __builtin_amdgcn_mfma_f32_16x16x32_bf16(aq1, b1, sacc[nt], 0, 0, 0);
    }

    // p = exp2(s); diagonal tile masks upper triangle
    if (kt == qt) {
      #pragma unroll
      for (int nt = 0; nt < 4; ++nt) {
        const int col = nt * 16 + l16;
        #pragma unroll
        for (int r = 0; r < 4; ++r) {
          const int row = wave * 16 + quad * 4 + r;
          float p = exp2f(sacc[nt][r]);
          p = (col <= row) ? p : 0.f;
          sacc[nt][r] = p; psum[r] += p;
        }
      }
    } else {
      #pragma unroll
      for (int nt = 0; nt < 4; ++nt)
        #pragma unroll
        for (int r = 0; r < 4; ++r) {
          const float p = exp2f(sacc[nt][r]);
          sacc[nt][r] = p; psum[r] += p;
        }
    }

    // P -> A-operand layout via per-wave LDS slice
    #pragma unroll
    for (int nt = 0; nt < 4; ++nt)
      #pragma unroll
      for (int r = 0; r < 4; ++r)
        QP[wave][quad * 4 + r][nt * 16 + l16] = f2bf_rtz(sacc[nt][r]);
    bf16x8 p0 = *(const bf16x8*)&QP[wave][l16][quad * 8];
    bf16x8 p1 = *(const bf16x8*)&QP[wave][l16][32 + quad * 8];

    // O += P @ V : B-frag [col=e=l16][k=t=quad*8+j] = Vs[e][t] row-major
    #pragma unroll
    for (int et = 0; et < 4; ++et) {
      bf16x8 b0 = *(const bf16x8*)&Vs[cur][et * 16 + l16][quad * 8];
      bf16x8 b1 = *(const bf16x8*)&Vs[cur][et * 16 + l16][32 + quad * 8];
      oacc[et] = __builtin_amdgcn_mfma_f32_16x16x32_bf16(p0, b0, oacc[et], 0, 0, 0);
      oacc[et] = __builtin_amdgcn_mfma_f32_16x16x32_bf16(p1, b1, oacc[et], 0, 0, 0);
    }

    if (pf) {
      const int nxt = 1 - cur;
      *(uint4*)&Ks[nxt][sm][sc] = kA; *(uint4*)&Ks[nxt][sm][sc + 8] = kB;
      *(uint4*)&Vs[nxt][sm][sc] = vA; *(uint4*)&Vs[nxt][sm][sc + 8] = vB;
    }
    __syncthreads();
  }

  // epilogue: row-sum reduce, normalize, transpose via LDS, coalesced stores
  #pragma unroll
  for (int off = 1; off < 16; off <<= 1)
    #pragma unroll
    for (int r = 0; r < 4; ++r)
      psum[r] += __shfl_xor(psum[r], off, 64);
  u16 (*Os)[72] = Ks[0];
  #pragma unroll
  for (int r = 0; r < 4; ++r) {
    const float rinv = 1.f / fmaxf(psum[r], 1e-20f);
    const int row = wave * 16 + quad * 4 + r;
    #pragma unroll
    for (int et = 0; et < 4; ++et)
      Os[row][et * 16 + l16] = f2bf(oacc[et][r] * rinv);
  }
  const int orow = wave * 16 + (lane >> 3), oe = (lane & 7) * 8;
  #pragma unroll
  for (int it = 0; it < 2; ++it) {
    const int rr = orow + it * 8;
    uint4 o = *(const uint4*)&Os[rr][oe];
    *(uint4*)(Om + ((long)(b * T_ + qt * 64 + rr)) * 4096 + h * 64 + oe) = o;
  }
}

// ---------------------------------------------------------------------------
// out[row] = LN(X[row] + bias + sum_p P4[p][row]) * g + be  (float4-vectorized)
template<int XBF, int OBF>
__global__ __launch_bounds__(256) void ln_sum4(
    const float* __restrict__ P4, const float* __restrict__ bias,
    const void* __restrict__ Xv, const float* __restrict__ g,
    const float* __restrict__ be, void* __restrict__ outv)
{
  __shared__ float red[8];
  const int row = blockIdx.x, tid = threadIdx.x;
  const long base = (long)row * D_;
  const int i0 = tid * 4;

  float4 a = *(const float4*)(bias + i0);
  #pragma unroll
  for (int p = 0; p < 4; ++p) {
    float4 pv = *(const float4*)(P4 + (long)p * 2097152 + base + i0);
    a.x += pv.x; a.y += pv.y; a.z += pv.z; a.w += pv.w;
  }
  float v4[4];
  if (XBF) {
    ushort4 xu = *(const ushort4*)((const u16*)Xv + base + i0);
    v4[0] = bf2f(xu.x) + a.x; v4[1] = bf2f(xu.y) + a.y;
    v4[2] = bf2f(xu.z) + a.z; v4[3] = bf2f(xu.w) + a.w;
  } else {
    float4 xv = *(const float4*)((const float*)Xv + base + i0);
    v4[0] = xv.x + a.x; v4[1] = xv.y + a.y;
    v4[2] = xv.z + a.z; v4[3] = xv.w + a.w;
  }
  float s = v4[0] + v4[1] + v4[2] + v4[3];
  #pragma unroll
  for (int off = 32; off > 0; off >>= 1) s += __shfl_down(s, off, 64);
  if ((tid & 63) == 0) red[tid >> 6] = s;
  __syncthreads();
  const float mu = (red[0] + red[1] + red[2] + red[3]) * (1.f / D_);
  float vs = 0.f;
  #pragma unroll
  for (int j = 0; j < 4; ++j) { const float d = v4[j] - mu; vs += d * d; }
  #pragma unroll
  for (int off = 32; off > 0; off >>= 1) vs += __shfl_down(vs, off, 64);
  __syncthreads();
  if ((tid & 63) == 0) red[tid >> 6] = vs;
  __syncthreads();
  const float rs = rsqrtf((red[0] + red[1] + red[2] + red[3]) * (1.f / D_) + 1e-5f);
  const float4 gv = *(const float4*)(g + i0);
  const float4 bev = *(const float4*)(be + i0);
  const float o0 = (v4[0] - mu) * rs * gv.x + bev.x;
  const float o1 = (v4[1] - mu) * rs * gv.y + bev.y;
  const float o2 = (v4[2] - mu) * rs * gv.z + bev.z;
  const float o3 = (v4[3] - mu) * rs * gv.w + bev.w;
  if (OBF) {
    ushort4 ou = { f2bf(o0), f2bf(o1), f2bf(o2), f2bf(o3) };
    *(ushort4*)((u16*)outv + base + i0) = ou;
  } else {
    float4 of = { o0, o1, o2, o3 };
    *(float4*)((float*)outv + base + i0) = of;
  }
}

// ---------------------------------------------------------------------------
extern "C" void kernel_launch(void* const* d_in, const int* in_sizes, int n_in,
                              void* d_out, int out_size, void* d_ws, size_t ws_size,
                              hipStream_t stream) {
  const float* x   = (const float*)d_in[0];
  const float* Wq  = (const float*)d_in[1];
  const float* Wk  = (const float*)d_in[2];
  const float* Wv  = (const float*)d_in[3];
  const float* Wo  = (const float*)d_in[4];
  const float* bo  = (const float*)d_in[5];
  const float* W1  = (const float*)d_in[6];
  const float* b1  = (const float*)d_in[7];
  const float* W2  = (const float*)d_in[8];
  const float* b2  = (const float*)d_in[9];
  const float* g1  = (const float*)d_in[10];
  const float* be1 = (const float*)d_in[11];
  const float* g2  = (const float*)d_in[12];
  const float* be2 = (const float*)d_in[13];
  float* out = (float*)d_out;

  u16* ws = (u16*)d_ws;
  u16* xb    = ws;                    // 2,097,152 u16
  u16* Wqkvt = xb + 2097152;          // 12,582,912
  u16* Wot   = Wqkvt + 12582912;      // 4,194,304 (row-permuted: [col][h*64+e])
  u16* W1t   = Wot + 4194304;         // 4,194,304
  u16* W2t   = W1t + 4194304;         // 4,194,304
  u16* q     = W2t + 4194304;         // 8,388,608  [bh][t][e]
  u16* k     = q + SZ_QKV;
  u16* v     = k + SZ_QKV;            // v_t: [bh][e][t]
  u16* Om    = v + SZ_QKV;            // 8,388,608  [b*T+t][h*64+e]
  float* P1 = (float*)q;              // split-K partials over q+k
  float* P2 = (float*)q;
  u16* x1  = v;
  u16* h1  = Om;

  dim3 blk(256);
  dim3 blk8(512);

  // single consolidated pre-pass
  prep<<<dim3(7168), blk, 0, stream>>>(x, Wq, Wk, Wv, Wo, W1, W2,
                                       xb, Wqkvt, Wot, W1t, W2t);

  // QKV: [2048,1024]@[1024,12288] -> scatter q/k row-major, v transposed
  gemm8b<2, 1024, 1024><<<dim3(768), blk8, 0, stream>>>(
      xb, Wqkvt, q, nullptr, 1024, 0, 0);

  // causal flash attention -> Om (head-major)
  attn_flash<<<dim3(128, 16), blk, 0, stream>>>(q, k, v, Om);

  // out projection, split-K=4 (Wot rows permuted to match head-major Om)
  gemm8b<3, 4096, 4096><<<dim3(64, 1, 4), blk8, 0, stream>>>(
      Om, Wot, (u16*)P1, nullptr, 1024, 1024, 1024);

  // x1 = LN(x + (sum partials + bo))
  ln_sum4<0, 1><<<dim3(2048), blk, 0, stream>>>(P1, bo, x, g1, be1, x1);

  // FF1: relu([2048,1024]@[1024,4096] + b1)
  gemm8b<1, 1024, 1024><<<dim3(256), blk8, 0, stream>>>(
      x1, W1t, h1, b1, 1024, 0, 4096);

  // FF2, split-K=4
  gemm8b<3, 4096, 4096><<<dim3(64, 1, 4), blk8, 0, stream>>>(
      h1, W2t, (u16*)P2, nullptr, 1024, 1024, 1024);

  // out = LN(x1 + (sum partials + b2))
  ln_sum4<1, 0><<<dim3(2048), blk, 0, stream>>>(P2, b2, x1, g2, be2, out);

  (void)in_sizes; (void)n_in; (void)out_size; (void)ws_size;
}

// Round 10
// 347.315 us; speedup vs baseline: 1.0971x; 1.0971x over previous
//
#include <hip/hip_runtime.h>

typedef unsigned short u16;
typedef __bf16 bf16x8 __attribute__((ext_vector_type(8)));
typedef float f32x4 __attribute__((ext_vector_type(4)));

#define B_ 2
#define T_ 1024
#define D_ 1024
#define H_ 64
#define HS_ 64
#define FF_ 4096
#define SZ_QKV 8388608L
// softmax in exp2 domain: scale = (1/sqrt(64)) * log2(e); folded into Q staging
#define S_SCALE 0.1803368801111f

__device__ __forceinline__ float bf2f(u16 u) {
  union { unsigned int v; float f; } x; x.v = ((unsigned int)u) << 16; return x.f;
}
__device__ __forceinline__ u16 f2bf(float f) {
  union { float f; unsigned int v; } x; x.f = f;
  unsigned int r = x.v + 0x7fffu + ((x.v >> 16) & 1u);
  return (u16)(r >> 16);
}
__device__ __forceinline__ u16 f2bf_rtz(float f) {
  union { float f; unsigned int v; } x; x.f = f;
  return (u16)(x.v >> 16);
}

typedef __attribute__((address_space(3))) unsigned int lds_u32;
typedef __attribute__((address_space(1))) const unsigned int glb_u32;
__device__ __forceinline__ void gload_lds16(const void* g, void* l) {
  __builtin_amdgcn_global_load_lds((glb_u32*)g, (lds_u32*)l, 16, 0, 0);
}

// ---------------------------------------------------------------------------
// Consolidated pre-pass: x cvt + all weight transpose/convert (+Wo row perm).
__global__ __launch_bounds__(256) void prep(
    const float* __restrict__ x, const float* __restrict__ Wq,
    const float* __restrict__ Wk, const float* __restrict__ Wv,
    const float* __restrict__ Wo, const float* __restrict__ W1,
    const float* __restrict__ W2,
    u16* __restrict__ xb, u16* __restrict__ Wqkvt, u16* __restrict__ Wot,
    u16* __restrict__ W1t, u16* __restrict__ W2t)
{
  __shared__ float tile[64][65];
  int id = blockIdx.x;
  if (id < 1024) {           // x: fp32 -> bf16, 2048 elems/block
    const long i = ((long)id * 256 + threadIdx.x) * 8;
    float4 a = *(const float4*)(x + i);
    float4 b = *(const float4*)(x + i + 4);
    union { uint4 v; u16 u[8]; } o;
    o.u[0]=f2bf(a.x); o.u[1]=f2bf(a.y); o.u[2]=f2bf(a.z); o.u[3]=f2bf(a.w);
    o.u[4]=f2bf(b.x); o.u[5]=f2bf(b.y); o.u[6]=f2bf(b.z); o.u[7]=f2bf(b.w);
    *(uint4*)(xb + i) = o.v;
    return;
  }
  id -= 1024;
  const float* in; u16* out; long ibase, obase; int in_rs, out_rs, r0, c0;
  if (id < 3072) {           // Wq/Wk/Wv: [64][1024][64] -> [w*4096+z*64+c][r]
    const int w = id >> 10, rem = id & 1023;
    const int z = rem >> 4, rt = rem & 15;
    in = (w == 0) ? Wq : (w == 1) ? Wk : Wv;
    ibase = (long)z * 65536; in_rs = 64; r0 = rt * 64; c0 = 0;
    out = Wqkvt + (long)w * 4194304;
    obase = (long)z * 65536; out_rs = 1024;
  } else if (id < 4096) {    // Wo row-permuted: Wot'[c][h*64+e] = Wo[e*64+h][c]
    const int rem = id - 3072;
    const int z = rem >> 4, ct = rem & 15;      // z = h
    in = Wo; ibase = (long)z * 1024; in_rs = 65536; r0 = 0; c0 = ct * 64;
    out = Wot; obase = (long)z * 64; out_rs = 4096;
  } else if (id < 5120) {    // W1 [1024][4096] -> W1t[c][r]
    const int rem = id - 4096;
    const int rt = rem >> 6, ct = rem & 63;
    in = W1; ibase = 0; in_rs = 4096; r0 = rt * 64; c0 = ct * 64;
    out = W1t; obase = 0; out_rs = 1024;
  } else {                   // W2 [4096][1024] -> W2t[c][r]
    const int rem = id - 5120;
    const int rt = rem >> 4, ct = rem & 15;
    in = W2; ibase = 0; in_rs = 1024; r0 = rt * 64; c0 = ct * 64;
    out = W2t; obase = 0; out_rs = 4096;
  }
  const int t = threadIdx.x, lr = t >> 4, lc4 = (t & 15) * 4;
  #pragma unroll
  for (int j = 0; j < 4; ++j) {
    float4 f = *(const float4*)(in + ibase + (long)(r0 + lr + j * 16) * in_rs + c0 + lc4);
    tile[lr + j * 16][lc4]     = f.x;
    tile[lr + j * 16][lc4 + 1] = f.y;
    tile[lr + j * 16][lc4 + 2] = f.z;
    tile[lr + j * 16][lc4 + 3] = f.w;
  }
  __syncthreads();
  const int cr = t >> 3, ch = t & 7;
  #pragma unroll
  for (int j2 = 0; j2 < 2; ++j2) {
    const int crr = cr + j2 * 32;
    union { uint4 v; u16 u[8]; } o;
    #pragma unroll
    for (int i = 0; i < 8; ++i) o.u[i] = f2bf(tile[ch * 8 + i][crr]);
    *(uint4*)(out + obase + (long)(c0 + crr) * out_rs + r0 + ch * 8) = o.v;
  }
}

// ---------------------------------------------------------------------------
// Minimal-barrier pipelined bf16 GEMM with register read-ahead (r8 structure).
// BM=256, BN=128, BK=64, 512 threads (8 waves, 4M x 2N), per-wave 64x64.
// Triple-buffered LDS, ONE s_barrier + ONE counted vmcnt(6) per K-tile.
// ALL 16 ds_read_b128 issued right after the barrier; compiler emits
// progressive counted lgkmcnt so each MFMA cluster's LDS wait overlaps the
// previous cluster's MFMAs. MFMA clusters k-sub-outer; epilogue j-innermost.
// LDS swizzle: stored chunk phys = log ^ (row&7) via pre-swizzled global src.
// EPI: 1 bias+relu->bf16, 2 QKV scatter (q,k row-major; V TRANSPOSED
// v_t[bh][e][t] stored as PACKED ushort4 over 4 consecutive t — same
// 32B-per-cache-line store efficiency as row-major, r9 lesson),
// 3 fp32 partial (no bias).
template<int EPI, int LDA, int LDB>
__global__ __launch_bounds__(512, 2) void gemm8b(
    const u16* __restrict__ A, const u16* __restrict__ Bt, u16* __restrict__ C,
    const float* __restrict__ bias, int K, int koff, int ldc)
{
  __shared__ __attribute__((aligned(16))) u16 As[3][256 * 64];  // 96 KiB
  __shared__ __attribute__((aligned(16))) u16 Bs[3][128 * 64];  // 48 KiB
  const int nwg = gridDim.x, cpx = nwg >> 3;
  const int sid = (blockIdx.x & 7) * cpx + (blockIdx.x >> 3);
  const int bm = sid & 7, bn = sid >> 3;
  const int bz = blockIdx.z;
  const long ko = (long)bz * koff;
  const int tid = threadIdx.x, wave = tid >> 6, lane = tid & 63;
  const int quad = lane >> 4, l16 = lane & 15;
  const int wm = (wave >> 1) * 64;            // 4 M-waves
  const int wn = (wave & 1) * 64;             // 2 N-waves
  const int slog = ((tid & 7) ^ ((tid >> 3) & 7)) * 8;  // staging src pre-swizzle
  const int srow = tid >> 3;                            // 0..63
  const int ph0 = ((quad)     ^ (l16 & 7)) * 8;         // k-sub 0
  const int ph1 = ((4 + quad) ^ (l16 & 7)) * 8;         // k-sub 1

  const u16* Ag = A + (long)(bm * 256) * LDA + ko + slog;
  const u16* Bg = Bt + (long)(bn * 128) * LDB + ko + slog;

  f32x4 acc[4][4];
  #pragma unroll
  for (int i = 0; i < 4; ++i)
    #pragma unroll
    for (int j = 0; j < 4; ++j) acc[i][j] = (f32x4){0.f, 0.f, 0.f, 0.f};

  const int nK = K >> 6;

  auto STAGE_A = [&](int d, int t, int a) {
    gload_lds16(Ag + (long)(a * 64 + srow) * LDA + (t << 6),
                (u16*)As[d] + a * 4096 + tid * 8);
  };
  auto STAGE_B = [&](int d, int t, int b) {
    gload_lds16(Bg + (long)(b * 64 + srow) * LDB + (t << 6),
                (u16*)Bs[d] + b * 4096 + tid * 8);
  };

  // prologue: tiles 0 and 1 fully staged
  #pragma unroll
  for (int a = 0; a < 4; ++a) STAGE_A(0, 0, a);
  STAGE_B(0, 0, 0); STAGE_B(0, 0, 1);
  #pragma unroll
  for (int a = 0; a < 4; ++a) STAGE_A(1, 1, a);
  STAGE_B(1, 1, 0); STAGE_B(1, 1, 1);

  bf16x8 af[4][2], bf[4][2];
  int cur = 0;
  for (int t = 0; t < nK; ++t) {
    const int nxt = (cur >= 1) ? cur - 1 : 2;   // (t+2)%3
    const bool st = (t + 2) < nK;
    const u16* Ab = As[cur];
    const u16* Bb = Bs[cur];

    if (t < nK - 1) { asm volatile("s_waitcnt vmcnt(6)" ::: "memory"); }
    else            { asm volatile("s_waitcnt vmcnt(0)" ::: "memory"); }
    __builtin_amdgcn_sched_barrier(0);
    __builtin_amdgcn_s_barrier();
    __builtin_amdgcn_sched_barrier(0);

    // issue ALL tile reads up front (a01,b01 -> b23 -> a23)
    #pragma unroll
    for (int ii = 0; ii < 2; ++ii) {
      const u16* r = Ab + (wm + ii * 16 + l16) * 64;
      af[ii][0] = *(const bf16x8*)(r + ph0);
      af[ii][1] = *(const bf16x8*)(r + ph1);
    }
    #pragma unroll
    for (int jj = 0; jj < 2; ++jj) {
      const u16* r = Bb + (wn + jj * 16 + l16) * 64;
      bf[jj][0] = *(const bf16x8*)(r + ph0);
      bf[jj][1] = *(const bf16x8*)(r + ph1);
    }
    #pragma unroll
    for (int jj = 0; jj < 2; ++jj) {
      const u16* r = Bb + (wn + (2 + jj) * 16 + l16) * 64;
      bf[2 + jj][0] = *(const bf16x8*)(r + ph0);
      bf[2 + jj][1] = *(const bf16x8*)(r + ph1);
    }
    #pragma unroll
    for (int ii = 0; ii < 2; ++ii) {
      const u16* r = Ab + (wm + (2 + ii) * 16 + l16) * 64;
      af[2 + ii][0] = *(const bf16x8*)(r + ph0);
      af[2 + ii][1] = *(const bf16x8*)(r + ph1);
    }

    // cluster 0: a01 x b01 (+ stage A0,A1 of t+2)
    if (st) { STAGE_A(nxt, t + 2, 0); STAGE_A(nxt, t + 2, 1); }
    __builtin_amdgcn_s_setprio(1);
    #pragma unroll
    for (int ks = 0; ks < 2; ++ks)
      #pragma unroll
      for (int ii = 0; ii < 2; ++ii)
        #pragma unroll
        for (int jj = 0; jj < 2; ++jj)
          acc[ii][jj] = __builtin_amdgcn_mfma_f32_16x16x32_bf16(af[ii][ks], bf[jj][ks], acc[ii][jj], 0, 0, 0);
    __builtin_amdgcn_s_setprio(0);

    // cluster 1: a01 x b23 (+ stage A2,A3 of t+2)
    if (st) { STAGE_A(nxt, t + 2, 2); STAGE_A(nxt, t + 2, 3); }
    __builtin_amdgcn_s_setprio(1);
    #pragma unroll
    for (int ks = 0; ks < 2; ++ks)
      #pragma unroll
      for (int ii = 0; ii < 2; ++ii)
        #pragma unroll
        for (int jj = 0; jj < 2; ++jj)
          acc[ii][2 + jj] = __builtin_amdgcn_mfma_f32_16x16x32_bf16(af[ii][ks], bf[2 + jj][ks], acc[ii][2 + jj], 0, 0, 0);
    __builtin_amdgcn_s_setprio(0);

    // cluster 2: a23 x b01 (+ stage B0,B1 of t+2)
    if (st) { STAGE_B(nxt, t + 2, 0); STAGE_B(nxt, t + 2, 1); }
    __builtin_amdgcn_s_setprio(1);
    #pragma unroll
    for (int ks = 0; ks < 2; ++ks)
      #pragma unroll
      for (int ii = 0; ii < 2; ++ii)
        #pragma unroll
        for (int jj = 0; jj < 2; ++jj)
          acc[2 + ii][jj] = __builtin_amdgcn_mfma_f32_16x16x32_bf16(af[2 + ii][ks], bf[jj][ks], acc[2 + ii][jj], 0, 0, 0);
    __builtin_amdgcn_s_setprio(0);

    // cluster 3: a23 x b23
    __builtin_amdgcn_s_setprio(1);
    #pragma unroll
    for (int ks = 0; ks < 2; ++ks)
      #pragma unroll
      for (int ii = 0; ii < 2; ++ii)
        #pragma unroll
        for (int jj = 0; jj < 2; ++jj)
          acc[2 + ii][2 + jj] = __builtin_amdgcn_mfma_f32_16x16x32_bf16(af[2 + ii][ks], bf[2 + jj][ks], acc[2 + ii][2 + jj], 0, 0, 0);
    __builtin_amdgcn_s_setprio(0);
    __builtin_amdgcn_sched_barrier(0);

    cur = (cur == 2) ? 0 : cur + 1;
  }

  // ---- epilogue ----
  if (EPI == 2 && bn >= 64) {
    // v-blocks: packed transposed store. acc[i][j][r=0..3] are 4 consecutive
    // t at v_t[e][ttb..ttb+3] -> one 8B ushort4 per (i,j); 4 quads fill 32B
    // per e-row (same per-line bytes as row-major store).
    const int bb = (bm * 256) >> 10;            // block entirely in one batch
    #pragma unroll
    for (int i = 0; i < 4; ++i) {
      const int ttb = bm * 256 + wm + i * 16 + quad * 4;
      const int tt = ttb & 1023;
      #pragma unroll
      for (int j = 0; j < 4; ++j) {
        const int rem = (bn * 128 + wn + j * 16 + l16) & 4095;
        const int h = rem >> 6, e = rem & 63;
        ushort4 o = { f2bf(acc[i][j][0]), f2bf(acc[i][j][1]),
                      f2bf(acc[i][j][2]), f2bf(acc[i][j][3]) };
        *(ushort4*)(C + 2L * SZ_QKV + ((long)((bb << 6) + h)) * 65536L
                    + (long)e * 1024 + tt) = o;
      }
    }
    return;
  }
  float bv[4];
  #pragma unroll
  for (int j = 0; j < 4; ++j)
    bv[j] = (EPI == 1) ? bias[bn * 128 + wn + j * 16 + l16] : 0.f;
  #pragma unroll
  for (int i = 0; i < 4; ++i) {
    #pragma unroll
    for (int r = 0; r < 4; ++r) {
      const int row = bm * 256 + wm + i * 16 + quad * 4 + r;
      #pragma unroll
      for (int j = 0; j < 4; ++j) {
        const int col = bn * 128 + wn + j * 16 + l16;
        float vv = acc[i][j][r] + bv[j];
        if (EPI == 1) vv = fmaxf(vv, 0.f);
        if (EPI == 2) {
          const int which = col >> 12, rem = col & 4095;
          const int h = rem >> 6, e = rem & 63;
          const int bb = row >> 10, tt = row & 1023;
          C[(long)which * SZ_QKV + ((long)((bb << 6) + h)) * 65536L + (long)tt * 64 + e] = f2bf(vv);
        } else if (EPI == 3) {
          ((float*)C)[(long)bz * 2097152 + (long)row * ldc + col] = vv;
        } else {
          C[(long)row * ldc + col] = f2bf(vv);
        }
      }
    }
  }
}

// ---------------------------------------------------------------------------
// Flash causal attention, no-max variant. Grid (B*H, 16). Block 256 (4 waves).
// V arrives TRANSPOSED from QKV (v_t[bh][e][t]) so Vs[e][t] staging is two
// vector ds_write_b128 per thread (identical to Ks). PV B-fragment reads are
// bit-identical in form to QK's Ks reads.
__global__ __launch_bounds__(256) void attn_flash(
    const u16* __restrict__ Q, const u16* __restrict__ Kg,
    const u16* __restrict__ Vt, u16* __restrict__ Om)
{
  __shared__ __attribute__((aligned(16))) u16 Ks[2][64][72];
  __shared__ __attribute__((aligned(16))) u16 Vs[2][64][72];   // [e][t]
  __shared__ __attribute__((aligned(16))) u16 QP[4][16][72];
  const int bh = blockIdx.x;
  const int qt = gridDim.y - 1 - blockIdx.y;   // longest first
  const int b = bh >> 6, h = bh & 63;
  const long base = (long)bh * (T_ * HS_);
  const int tid = threadIdx.x;
  const int wave = tid >> 6, lane = tid & 63, quad = lane >> 4, l16 = lane & 15;
  const int sm = tid >> 2, sc = (tid & 3) * 16;

  // stage Q per-wave, pre-scaled by S_SCALE
  {
    const int qr = lane >> 3, qe = (lane & 7) * 8;
    #pragma unroll
    for (int j = 0; j < 2; ++j) {
      union { uint4 v; u16 u[8]; } a, o;
      a.v = *(const uint4*)(Q + base + (long)(qt * 64 + wave * 16 + qr + j * 8) * HS_ + qe);
      #pragma unroll
      for (int i = 0; i < 8; ++i) o.u[i] = f2bf(bf2f(a.u[i]) * S_SCALE);
      *(uint4*)&QP[wave][qr + j * 8][qe] = o.v;
    }
  }
  bf16x8 aq0 = *(const bf16x8*)&QP[wave][l16][quad * 8];
  bf16x8 aq1 = *(const bf16x8*)&QP[wave][l16][32 + quad * 8];

  float psum[4] = { 0.f, 0.f, 0.f, 0.f };
  f32x4 oacc[4] = { {0,0,0,0}, {0,0,0,0}, {0,0,0,0}, {0,0,0,0} };

  // K tile rows: K[t=sm][e=sc..]; V tile rows: v_t[e=sm][t=kt*64+sc..]
  uint4 kA, kB, vA, vB;
  kA = *(const uint4*)(Kg + base + (long)sm * HS_ + sc);
  kB = *(const uint4*)(Kg + base + (long)sm * HS_ + sc + 8);
  vA = *(const uint4*)(Vt + base + (long)sm * 1024 + sc);
  vB = *(const uint4*)(Vt + base + (long)sm * 1024 + sc + 8);
  {
    *(uint4*)&Ks[0][sm][sc] = kA; *(uint4*)&Ks[0][sm][sc + 8] = kB;
    *(uint4*)&Vs[0][sm][sc] = vA; *(uint4*)&Vs[0][sm][sc + 8] = vB;
  }
  __syncthreads();

  for (int kt = 0; kt <= qt; ++kt) {
    const int cur = kt & 1;
    const bool pf = (kt < qt);
    if (pf) {
      kA = *(const uint4*)(Kg + base + (long)((kt + 1) * 64 + sm) * HS_ + sc);
      kB = *(const uint4*)(Kg + base + (long)((kt + 1) * 64 + sm) * HS_ + sc + 8);
      vA = *(const uint4*)(Vt + base + (long)sm * 1024 + (kt + 1) * 64 + sc);
      vB = *(const uint4*)(Vt + base + (long)sm * 1024 + (kt + 1) * 64 + sc + 8);
    }

    // S = Q @ K^T
    f32x4 sacc[4] = { {0,0,0,0}, {0,0,0,0}, {0,0,0,0}, {0,0,0,0} };
    #pragma unroll
    for (int nt = 0; nt < 4; ++nt) {
      bf16x8 b0 = *(const bf16x8*)&Ks[cur][nt * 16 + l16][quad * 8];
      bf16x8 b1 = *(const bf16x8*)&Ks[cur][nt * 16 + l16][32 + quad * 8];
      sacc[nt] = __builtin_amdgcn_mfma_f32_16x16x32_bf16(aq0, b0, sacc[nt], 0, 0, 0);
      sacc[nt] = __builtin_amdgcn_mfma_f32_16x16x32_bf16(aq1, b1, sacc[nt], 0, 0, 0);
    }

    // p = exp2(s); diagonal tile masks upper triangle
    if (kt == qt) {
      #pragma unroll
      for (int nt = 0; nt < 4; ++nt) {
        const int col = nt * 16 + l16;
        #pragma unroll
        for (int r = 0; r < 4; ++r) {
          const int row = wave * 16 + quad * 4 + r;
          float p = exp2f(sacc[nt][r]);
          p = (col <= row) ? p : 0.f;
          sacc[nt][r] = p; psum[r] += p;
        }
      }
    } else {
      #pragma unroll
      for (int nt = 0; nt < 4; ++nt)
        #pragma unroll
        for (int r = 0; r < 4; ++r) {
          const float p = exp2f(sacc[nt][r]);
          sacc[nt][r] = p; psum[r] += p;
        }
    }

    // P -> A-operand layout via per-wave LDS slice
    #pragma unroll
    for (int nt = 0; nt < 4; ++nt)
      #pragma unroll
      for (int r = 0; r < 4; ++r)
        QP[wave][quad * 4 + r][nt * 16 + l16] = f2bf_rtz(sacc[nt][r]);
    bf16x8 p0 = *(const bf16x8*)&QP[wave][l16][quad * 8];
    bf16x8 p1 = *(const bf16x8*)&QP[wave][l16][32 + quad * 8];

    // O += P @ V : B-frag [col=e=l16][k=t=quad*8+j] = Vs[e][t] row-major
    #pragma unroll
    for (int et = 0; et < 4; ++et) {
      bf16x8 b0 = *(const bf16x8*)&Vs[cur][et * 16 + l16][quad * 8];
      bf16x8 b1 = *(const bf16x8*)&Vs[cur][et * 16 + l16][32 + quad * 8];
      oacc[et] = __builtin_amdgcn_mfma_f32_16x16x32_bf16(p0, b0, oacc[et], 0, 0, 0);
      oacc[et] = __builtin_amdgcn_mfma_f32_16x16x32_bf16(p1, b1, oacc[et], 0, 0, 0);
    }

    if (pf) {
      const int nxt = 1 - cur;
      *(uint4*)&Ks[nxt][sm][sc] = kA; *(uint4*)&Ks[nxt][sm][sc + 8] = kB;
      *(uint4*)&Vs[nxt][sm][sc] = vA; *(uint4*)&Vs[nxt][sm][sc + 8] = vB;
    }
    __syncthreads();
  }

  // epilogue: row-sum reduce, normalize, transpose via LDS, coalesced stores
  #pragma unroll
  for (int off = 1; off < 16; off <<= 1)
    #pragma unroll
    for (int r = 0; r < 4; ++r)
      psum[r] += __shfl_xor(psum[r], off, 64);
  u16 (*Os)[72] = Ks[0];
  #pragma unroll
  for (int r = 0; r < 4; ++r) {
    const float rinv = 1.f / fmaxf(psum[r], 1e-20f);
    const int row = wave * 16 + quad * 4 + r;
    #pragma unroll
    for (int et = 0; et < 4; ++et)
      Os[row][et * 16 + l16] = f2bf(oacc[et][r] * rinv);
  }
  const int orow = wave * 16 + (lane >> 3), oe = (lane & 7) * 8;
  #pragma unroll
  for (int it = 0; it < 2; ++it) {
    const int rr = orow + it * 8;
    uint4 o = *(const uint4*)&Os[rr][oe];
    *(uint4*)(Om + ((long)(b * T_ + qt * 64 + rr)) * 4096 + h * 64 + oe) = o;
  }
}

// ---------------------------------------------------------------------------
// out[row] = LN(X[row] + bias + sum_p P4[p][row]) * g + be  (float4-vectorized)
template<int XBF, int OBF>
__global__ __launch_bounds__(256) void ln_sum4(
    const float* __restrict__ P4, const float* __restrict__ bias,
    const void* __restrict__ Xv, const float* __restrict__ g,
    const float* __restrict__ be, void* __restrict__ outv)
{
  __shared__ float red[8];
  const int row = blockIdx.x, tid = threadIdx.x;
  const long base = (long)row * D_;
  const int i0 = tid * 4;

  float4 a = *(const float4*)(bias + i0);
  #pragma unroll
  for (int p = 0; p < 4; ++p) {
    float4 pv = *(const float4*)(P4 + (long)p * 2097152 + base + i0);
    a.x += pv.x; a.y += pv.y; a.z += pv.z; a.w += pv.w;
  }
  float v4[4];
  if (XBF) {
    ushort4 xu = *(const ushort4*)((const u16*)Xv + base + i0);
    v4[0] = bf2f(xu.x) + a.x; v4[1] = bf2f(xu.y) + a.y;
    v4[2] = bf2f(xu.z) + a.z; v4[3] = bf2f(xu.w) + a.w;
  } else {
    float4 xv = *(const float4*)((const float*)Xv + base + i0);
    v4[0] = xv.x + a.x; v4[1] = xv.y + a.y;
    v4[2] = xv.z + a.z; v4[3] = xv.w + a.w;
  }
  float s = v4[0] + v4[1] + v4[2] + v4[3];
  #pragma unroll
  for (int off = 32; off > 0; off >>= 1) s += __shfl_down(s, off, 64);
  if ((tid & 63) == 0) red[tid >> 6] = s;
  __syncthreads();
  const float mu = (red[0] + red[1] + red[2] + red[3]) * (1.f / D_);
  float vs = 0.f;
  #pragma unroll
  for (int j = 0; j < 4; ++j) { const float d = v4[j] - mu; vs += d * d; }
  #pragma unroll
  for (int off = 32; off > 0; off >>= 1) vs += __shfl_down(vs, off, 64);
  __syncthreads();
  if ((tid & 63) == 0) red[tid >> 6] = vs;
  __syncthreads();
  const float rs = rsqrtf((red[0] + red[1] + red[2] + red[3]) * (1.f / D_) + 1e-5f);
  const float4 gv = *(const float4*)(g + i0);
  const float4 bev = *(const float4*)(be + i0);
  const float o0 = (v4[0] - mu) * rs * gv.x + bev.x;
  const float o1 = (v4[1] - mu) * rs * gv.y + bev.y;
  const float o2 = (v4[2] - mu) * rs * gv.z + bev.z;
  const float o3 = (v4[3] - mu) * rs * gv.w + bev.w;
  if (OBF) {
    ushort4 ou = { f2bf(o0), f2bf(o1), f2bf(o2), f2bf(o3) };
    *(ushort4*)((u16*)outv + base + i0) = ou;
  } else {
    float4 of = { o0, o1, o2, o3 };
    *(float4*)((float*)outv + base + i0) = of;
  }
}

// ---------------------------------------------------------------------------
extern "C" void kernel_launch(void* const* d_in, const int* in_sizes, int n_in,
                              void* d_out, int out_size, void* d_ws, size_t ws_size,
                              hipStream_t stream) {
  const float* x   = (const float*)d_in[0];
  const float* Wq  = (const float*)d_in[1];
  const float* Wk  = (const float*)d_in[2];
  const float* Wv  = (const float*)d_in[3];
  const float* Wo  = (const float*)d_in[4];
  const float* bo  = (const float*)d_in[5];
  const float* W1  = (const float*)d_in[6];
  const float* b1  = (const float*)d_in[7];
  const float* W2  = (const float*)d_in[8];
  const float* b2  = (const float*)d_in[9];
  const float* g1  = (const float*)d_in[10];
  const float* be1 = (const float*)d_in[11];
  const float* g2  = (const float*)d_in[12];
  const float* be2 = (const float*)d_in[13];
  float* out = (float*)d_out;

  u16* ws = (u16*)d_ws;
  u16* xb    = ws;                    // 2,097,152 u16
  u16* Wqkvt = xb + 2097152;          // 12,582,912
  u16* Wot   = Wqkvt + 12582912;      // 4,194,304 (row-permuted: [col][h*64+e])
  u16* W1t   = Wot + 4194304;         // 4,194,304
  u16* W2t   = W1t + 4194304;         // 4,194,304
  u16* q     = W2t + 4194304;         // 8,388,608  [bh][t][e]
  u16* k     = q + SZ_QKV;
  u16* v     = k + SZ_QKV;            // v_t: [bh][e][t]
  u16* Om    = v + SZ_QKV;            // 8,388,608  [b*T+t][h*64+e]
  float* P1 = (float*)q;              // split-K partials over q+k
  float* P2 = (float*)q;
  u16* x1  = v;
  u16* h1  = Om;

  dim3 blk(256);
  dim3 blk8(512);

  // single consolidated pre-pass
  prep<<<dim3(7168), blk, 0, stream>>>(x, Wq, Wk, Wv, Wo, W1, W2,
                                       xb, Wqkvt, Wot, W1t, W2t);

  // QKV: [2048,1024]@[1024,12288] -> scatter q/k row-major, v transposed(packed)
  gemm8b<2, 1024, 1024><<<dim3(768), blk8, 0, stream>>>(
      xb, Wqkvt, q, nullptr, 1024, 0, 0);

  // causal flash attention -> Om (head-major)
  attn_flash<<<dim3(128, 16), blk, 0, stream>>>(q, k, v, Om);

  // out projection, split-K=4 (Wot rows permuted to match head-major Om)
  gemm8b<3, 4096, 4096><<<dim3(64, 1, 4), blk8, 0, stream>>>(
      Om, Wot, (u16*)P1, nullptr, 1024, 1024, 1024);

  // x1 = LN(x + (sum partials + bo))
  ln_sum4<0, 1><<<dim3(2048), blk, 0, stream>>>(P1, bo, x, g1, be1, x1);

  // FF1: relu([2048,1024]@[1024,4096] + b1)
  gemm8b<1, 1024, 1024><<<dim3(256), blk8, 0, stream>>>(
      x1, W1t, h1, b1, 1024, 0, 4096);

  // FF2, split-K=4
  gemm8b<3, 4096, 4096><<<dim3(64, 1, 4), blk8, 0, stream>>>(
      h1, W2t, (u16*)P2, nullptr, 1024, 1024, 1024);

  // out = LN(x1 + (sum partials + b2))
  ln_sum4<1, 0><<<dim3(2048), blk, 0, stream>>>(P2, b2, x1, g2, be2, out);

  (void)in_sizes; (void)n_in; (void)out_size; (void)ws_size;
}